// Round 4
// baseline (156.754 us; speedup 1.0000x reference)
//
#include <hip/hip_runtime.h>
#include <stdint.h>

// YatConv: y = scale * (dot^2 / (||patch||^2 - 2*dot + ||W_o||^2 + eps) + bias)
// x: [16][64][64][128] f32, kernel: [3][3][128][256] f32 (HWIO), out: [16][64][64][256] f32
// Implicit GEMM: M=65536 pixels, N=256 out-channels, K=1152, bf16 MFMA.
// v3: v2 minus the mid-iteration full-drain barrier — reads and MFMAs now overlap
//     (compiler inserts counted lgkmcnt); anti-clobber moved to a post-MFMA barrier.
//     prep_x rewritten grid-stride (4096 waves) to kill tiny-wave launch overhead.

#define HH 64
#define WW 64
#define CC 128
#define OO 256
#define HP 66
#define WP 66
#define NPIX (16 * HP * WP)   // 69696 padded pixels
#define KTOT 1152
#define NKT 18
#define EPSV 1e-5f

#define BM 256
#define BN 128
#define SLOT_BYTES 49152   // A 32KB + B 16KB per K-tile buffer
#define B_OFF 32768
#define SMEM_TOTAL (3 * SLOT_BYTES + 1024)

typedef short short8 __attribute__((ext_vector_type(8)));
typedef float f32x4 __attribute__((ext_vector_type(4)));

__device__ __forceinline__ unsigned short f2bf(float f) {
  unsigned u = __builtin_bit_cast(unsigned, f);
  u += 0x7fffu + ((u >> 16) & 1u);   // round-to-nearest-even
  return (unsigned short)(u >> 16);
}

__device__ __forceinline__ void gload_lds16(const void* g, void* l) {
  __builtin_amdgcn_global_load_lds(
      (const __attribute__((address_space(1))) unsigned int*)g,
      (__attribute__((address_space(3))) unsigned int*)l,
      16, 0, 0);
}

#define FENCE() asm volatile("" ::: "memory")
#define BAR() do { FENCE(); __builtin_amdgcn_s_barrier(); FENCE(); } while (0)

// ---- prep 1: x (f32) -> padded bf16 [16][66][66][128] halo-zeroed, + s2p (f32).
//      Grid-stride: 4096 waves, ~17 pixels each (v2's 69696 one-shot waves were
//      launch/retire-bound). Inner math unchanged from the verified version.
__global__ __launch_bounds__(256) void prep_x(const float* __restrict__ x,
                                              unsigned short* __restrict__ xp,
                                              float* __restrict__ s2p) {
  int lane = threadIdx.x & 63;
  int wv = (blockIdx.x << 2) + (threadIdx.x >> 6);
  for (int gw = wv; gw < NPIX; gw += 4096) {
    int b = gw / (HP * WP);
    int rem = gw - b * (HP * WP);
    int hp = rem / WP;
    int wp = rem - hp * WP;
    float2 v = make_float2(0.f, 0.f);
    if (hp >= 1 && hp <= HH && wp >= 1 && wp <= WW) {
      const float2* src = (const float2*)(x + (size_t)(((b * HH) + hp - 1) * WW + (wp - 1)) * CC);
      v = src[lane];
    }
    ushort2 o2;
    o2.x = f2bf(v.x);
    o2.y = f2bf(v.y);
    ((ushort2*)(xp + (size_t)gw * CC))[lane] = o2;
    float ss = v.x * v.x + v.y * v.y;
    #pragma unroll
    for (int off = 32; off > 0; off >>= 1) ss += __shfl_down(ss, off);
    if (lane == 0) s2p[gw] = ss;
  }
}

// ---- prep 2: unchanged (cost-model says ~3-5 us; not worth risk yet) ----
__global__ __launch_bounds__(256) void prep_w(const float* __restrict__ kern,
                                              unsigned short* __restrict__ wt,
                                              float* __restrict__ ksq) {
  int o = blockIdx.x;
  int t = threadIdx.x;
  float acc = 0.f;
  for (int k = t; k < KTOT; k += 256) {
    float v = kern[(size_t)k * OO + o];
    wt[(size_t)o * KTOT + k] = f2bf(v);
    acc += v * v;
  }
  __shared__ float red[256];
  red[t] = acc;
  __syncthreads();
  #pragma unroll
  for (int s = 128; s > 0; s >>= 1) {
    if (t < s) red[t] += red[t + s];
    __syncthreads();
  }
  if (t == 0) ksq[o] = red[0];
}

// ---- main v3 ----
__global__ __launch_bounds__(512, 2) void yat_main(
    const unsigned short* __restrict__ xp,
    const unsigned short* __restrict__ wt,
    const float* __restrict__ s2p,
    const float* __restrict__ ksq,
    const float* __restrict__ bias,
    const float* __restrict__ alpha,
    float* __restrict__ out) {
  extern __shared__ char smem[];

  int tid = threadIdx.x;
  int wid = tid >> 6, lane = tid & 63;

  int bid = blockIdx.x;
  int swz = ((bid & 7) << 6) + (bid >> 3);   // bijective, 512 = 8*64
  int mt = swz >> 1, nt = swz & 1;           // N innermost: pairs share A panel
  int m0 = mt << 8;
  int n0 = nt << 7;

  // ---- staging source addresses (pre-swizzled: chunk cg = (tid&7) ^ ((tid>>3)&7))
  int cg = (((tid & 7) ^ ((tid >> 3) & 7)) << 3);   // half-elements
  const unsigned short* aSrc[4];
  #pragma unroll
  for (int q = 0; q < 4; ++q) {
    int r = (q << 6) + (tid >> 3);
    int p = m0 + r;
    int b = p >> 12, h = (p >> 6) & 63, w = p & 63;
    aSrc[q] = xp + (size_t)((b * HP + h) * WP + w) * CC + cg;
  }
  const unsigned short* bSrc[2];
  #pragma unroll
  for (int q = 0; q < 2; ++q) {
    int r = (q << 6) + (tid >> 3);
    bSrc[q] = wt + (size_t)(n0 + r) * KTOT + cg;
  }

  auto STAGE = [&](int t, int soff) {
    int tap = t >> 1;
    int dy = tap / 3;
    int dx = tap - dy * 3;
    int koff = (dy * WP + dx) * CC + ((t & 1) << 6);   // halfs
    char* da = smem + soff + (wid << 10);              // wave-uniform; HW adds lane*16
    #pragma unroll
    for (int q = 0; q < 4; ++q)
      gload_lds16(aSrc[q] + koff, da + (q << 13));
    int kb = t << 6;
    char* db = smem + soff + B_OFF + (wid << 10);
    #pragma unroll
    for (int q = 0; q < 2; ++q)
      gload_lds16(bSrc[q] + kb, db + (q << 13));
  };

  // ---- fragment read offsets (swizzled: chunk' = chunk ^ (row&7), row&7 == lane&7)
  int wr = wid >> 1, wcn = wid & 1;
  int rA0 = (wr << 6) + (lane & 15);
  int rB0 = (wcn << 6) + (lane & 15);
  int xsw = lane & 7;
  int co0 = (((lane >> 4) ^ xsw) << 4);          // ks=0 chunk byte offset
  int co1 = ((((lane >> 4) + 4) ^ xsw) << 4);    // ks=1

  f32x4 acc[4][4] = {};

  STAGE(0, 0);
  STAGE(1, SLOT_BYTES);

  int soff = 0;
  int stoff = 2 * SLOT_BYTES;
  for (int i = 0; i < NKT; ++i) {
    if (i < NKT - 2) STAGE(i + 2, stoff);
    // counted wait: tile i's 6 loads are the oldest outstanding
    if (i < NKT - 2)      asm volatile("s_waitcnt vmcnt(12)" ::: "memory");
    else if (i == NKT - 2) asm volatile("s_waitcnt vmcnt(6)" ::: "memory");
    else                   asm volatile("s_waitcnt vmcnt(0)" ::: "memory");
    BAR();   // [BAR1] all waves' tile-i DMAs landed

    const char* Ab = smem + soff;
    const char* Bb = Ab + B_OFF;
    short8 af[2][4], bf[2][4];
    #pragma unroll
    for (int ks = 0; ks < 2; ++ks) {
      int co = ks ? co1 : co0;
      #pragma unroll
      for (int m = 0; m < 4; ++m)
        af[ks][m] = *(const short8*)(Ab + ((rA0 + (m << 4)) << 7) + co);
      #pragma unroll
      for (int n = 0; n < 4; ++n)
        bf[ks][n] = *(const short8*)(Bb + ((rB0 + (n << 4)) << 7) + co);
    }
    // NO drain here (v2's lockstep bug): compiler inserts counted lgkmcnt so
    // MFMA ks=0 starts while ks=1 reads are in flight; waves desync so one
    // wave's reads overlap another's MFMAs.
    __builtin_amdgcn_s_setprio(1);
    #pragma unroll
    for (int ks = 0; ks < 2; ++ks) {
      #pragma unroll
      for (int m = 0; m < 4; ++m) {
        #pragma unroll
        for (int n = 0; n < 4; ++n)
          acc[m][n] = __builtin_amdgcn_mfma_f32_16x16x32_bf16(af[ks][m], bf[ks][n], acc[m][n], 0, 0, 0);
      }
    }
    __builtin_amdgcn_s_setprio(0);
    asm volatile("s_waitcnt lgkmcnt(0)" ::: "memory");
    BAR();   // [BAR2] all waves done reading slot i -> iter i+1 may stage over (i+3)%3

    soff += SLOT_BYTES;  if (soff == 3 * SLOT_BYTES) soff = 0;
    stoff += SLOT_BYTES; if (stoff == 3 * SLOT_BYTES) stoff = 0;
  }

  // ---- epilogue ----
  float* ps = (float*)(smem + 3 * SLOT_BYTES);
  if (tid < BM) {
    int p = m0 + tid;
    int b = p >> 12, h = (p >> 6) & 63, w = p & 63;
    const float* s2 = s2p + (b * HP + h) * WP + w;   // top-left of 3x3 in padded coords
    float s = 0.f;
    #pragma unroll
    for (int dy = 0; dy < 3; ++dy) {
      #pragma unroll
      for (int dx = 0; dx < 3; ++dx) s += s2[dy * WP + dx];
    }
    ps[tid] = s;
  }
  asm volatile("s_waitcnt lgkmcnt(0)" ::: "memory");
  BAR();

  float al = alpha[0];
  float scale = powf(16.0f / logf(257.0f), al);   // (sqrt(256)/log1p(256))^alpha

  int c0 = n0 + (wcn << 6) + (lane & 15);
  int rb = (wr << 6) + ((lane >> 4) << 2);
  #pragma unroll
  for (int n = 0; n < 4; ++n) {
    int cn = c0 + (n << 4);
    float kq = ksq[cn] + EPSV;
    float bv = bias[cn];
    #pragma unroll
    for (int m = 0; m < 4; ++m) {
      f32x4 a = acc[m][n];
      #pragma unroll
      for (int j = 0; j < 4; ++j) {
        int rm = rb + (m << 4) + j;
        float dot = a[j];
        float dist = ps[rm] - 2.0f * dot + kq;
        float y = dot * dot / dist + bv;
        out[(size_t)(m0 + rm) * OO + cn] = y * scale;
      }
    }
  }
}

extern "C" void kernel_launch(void* const* d_in, const int* in_sizes, int n_in,
                              void* d_out, int out_size, void* d_ws, size_t ws_size,
                              hipStream_t stream) {
  const float* x = (const float*)d_in[0];
  const float* kern = (const float*)d_in[1];
  const float* bias = (const float*)d_in[2];
  const float* alpha = (const float*)d_in[3];
  float* out = (float*)d_out;

  char* ws = (char*)d_ws;
  unsigned short* xp  = (unsigned short*)ws;                 // 16*66*66*128*2 = 17,842,176 B
  unsigned short* wtb = (unsigned short*)(ws + 17842176);    // 256*1152*2    =    589,824 B
  float* s2p = (float*)(ws + 18432000);                      // 16*66*66*4    =    278,784 B
  float* ksq = (float*)(ws + 18710784);                      // 256*4         =      1,024 B

  // unconditional (no static guards per harness contract); host-side, capture-safe
  (void)hipFuncSetAttribute((const void*)yat_main,
                            hipFuncAttributeMaxDynamicSharedMemorySize, SMEM_TOTAL);

  prep_x<<<1024, 256, 0, stream>>>(x, xp, s2p);
  prep_w<<<256, 256, 0, stream>>>(kern, wtb, ksq);
  yat_main<<<512, 512, SMEM_TOTAL, stream>>>(xp, wtb, s2p, ksq, bias, alpha, out);
}

// Round 9
// 150.859 us; speedup vs baseline: 1.0391x; 1.0391x over previous
//
#include <hip/hip_runtime.h>
#include <stdint.h>

// YatConv: y = scale * (dot^2 / (||patch||^2 - 2*dot + ||W_o||^2 + eps) + bias)
// x: [16][64][64][128] f32, kernel: [3][3][128][256] f32 (HWIO), out: [16][64][64][256] f32
// Implicit GEMM: M=65536 pixels, N=256 out-channels, K=1152, bf16 MFMA.
// v4 (fourth resubmit; rounds 5-8 were infra failures, kernel never ran):
//     m201 8-phase-template port. BM=256 BN=256 BK=32, grid=256 (1 block/CU),
//     8 waves x (128x64), ring-4 LDS slots, 2 phases/K-tile with per-phase
//     {reads | barrier | stage | lgkm0 | 16 MFMA}, vmcnt(6) once per K-tile,
//     chunk^=(row>>1)&3 swizzle (pre-swizzled DMA source + swizzled read).

#define HH 64
#define WW 64
#define CC 128
#define OO 256
#define HP 66
#define WP 66
#define NPIX (16 * HP * WP)
#define KTOT 1152
#define BK 32
#define NKT 36
#define EPSV 1e-5f

#define SLOT 16384          // 256 rows x 32 k x 2B
#define A_BASE 0
#define B_BASE 65536
#define PS_OFF 131072
#define SMEM_TOTAL (131072 + 1024)

typedef short short8 __attribute__((ext_vector_type(8)));
typedef float f32x4 __attribute__((ext_vector_type(4)));

__device__ __forceinline__ unsigned short f2bf(float f) {
  unsigned u = __builtin_bit_cast(unsigned, f);
  u += 0x7fffu + ((u >> 16) & 1u);   // round-to-nearest-even
  return (unsigned short)(u >> 16);
}

__device__ __forceinline__ void gload_lds16(const void* g, void* l) {
  __builtin_amdgcn_global_load_lds(
      (const __attribute__((address_space(1))) unsigned int*)g,
      (__attribute__((address_space(3))) unsigned int*)l,
      16, 0, 0);
}

#define FENCE() asm volatile("" ::: "memory")
#define BAR() do { FENCE(); __builtin_amdgcn_s_barrier(); FENCE(); } while (0)

// ---- prep 1: x (f32) -> padded bf16 [16][66][66][128] halo-zeroed, + s2p (f32).
__global__ __launch_bounds__(256) void prep_x(const float* __restrict__ x,
                                              unsigned short* __restrict__ xp,
                                              float* __restrict__ s2p) {
  int lane = threadIdx.x & 63;
  int wv = (blockIdx.x << 2) + (threadIdx.x >> 6);
  for (int gw = wv; gw < NPIX; gw += 4096) {
    int b = gw / (HP * WP);
    int rem = gw - b * (HP * WP);
    int hp = rem / WP;
    int wp = rem - hp * WP;
    float2 v = make_float2(0.f, 0.f);
    if (hp >= 1 && hp <= HH && wp >= 1 && wp <= WW) {
      const float2* src = (const float2*)(x + (size_t)(((b * HH) + hp - 1) * WW + (wp - 1)) * CC);
      v = src[lane];
    }
    ushort2 o2;
    o2.x = f2bf(v.x);
    o2.y = f2bf(v.y);
    ((ushort2*)(xp + (size_t)gw * CC))[lane] = o2;
    float ss = v.x * v.x + v.y * v.y;
    #pragma unroll
    for (int off = 32; off > 0; off >>= 1) ss += __shfl_down(ss, off);
    if (lane == 0) s2p[gw] = ss;
  }
}

// ---- prep 2: kernel -> Wt [256][1152] bf16 + ksq ----
__global__ __launch_bounds__(256) void prep_w(const float* __restrict__ kern,
                                              unsigned short* __restrict__ wt,
                                              float* __restrict__ ksq) {
  int o = blockIdx.x;
  int t = threadIdx.x;
  float acc = 0.f;
  for (int k = t; k < KTOT; k += 256) {
    float v = kern[(size_t)k * OO + o];
    wt[(size_t)o * KTOT + k] = f2bf(v);
    acc += v * v;
  }
  __shared__ float red[256];
  red[t] = acc;
  __syncthreads();
  #pragma unroll
  for (int s = 128; s > 0; s >>= 1) {
    if (t < s) red[t] += red[t + s];
    __syncthreads();
  }
  if (t == 0) ksq[o] = red[0];
}

// ---- main v4 ----
__global__ __launch_bounds__(512, 2) void yat_main(
    const unsigned short* __restrict__ xp,
    const unsigned short* __restrict__ wt,
    const float* __restrict__ s2p,
    const float* __restrict__ ksq,
    const float* __restrict__ bias,
    const float* __restrict__ alpha,
    float* __restrict__ out) {
  extern __shared__ char smem[];

  int tid = threadIdx.x;
  int wid = tid >> 6, lane = tid & 63;

  int bid = blockIdx.x;
  int mt = ((bid & 7) << 5) + (bid >> 3);   // bijective XCD swizzle, 256 = 8*32
  int m0 = mt << 8;

  // ---- staging geometry: per wave 2 A-DMAs + 2 B-DMAs per K-tile.
  // lane l -> row = 32*wid + d*16 + (l>>2), lds chunk c = l&3;
  // source chunk g = c ^ ((l>>3)&3)  (inverse of read swizzle chunk^=(row>>1)&3).
  int g = ((lane & 3) ^ ((lane >> 3) & 3)) << 3;   // shorts (x8 = 16B)
  const unsigned short* aS[2];
  #pragma unroll
  for (int d = 0; d < 2; ++d) {
    int p = m0 + (wid << 5) + (d << 4) + (lane >> 2);
    int b = p >> 12, h = (p >> 6) & 63, w = p & 63;
    aS[d] = xp + (size_t)((b * HP + h) * WP + w) * CC + g;
  }
  const unsigned short* bS[2];
  #pragma unroll
  for (int d = 0; d < 2; ++d) {
    int o = (wid << 5) + (d << 4) + (lane >> 2);
    bS[d] = wt + (size_t)o * KTOT + g;
  }

  auto STAGE_A = [&](int t) {
    int tap = t >> 2, q = t & 3;
    int dy = tap / 3, dx = tap - dy * 3;
    int koff = (dy * WP + dx) * CC + (q << 5);       // shorts
    char* dst = smem + A_BASE + ((t & 3) << 14) + (wid << 11);
    gload_lds16(aS[0] + koff, dst);
    gload_lds16(aS[1] + koff, dst + 1024);
  };
  auto STAGE_B = [&](int t) {
    int koff = t << 5;                               // shorts (contiguous k per o)
    char* dst = smem + B_BASE + ((t & 3) << 14) + (wid << 11);
    gload_lds16(bS[0] + koff, dst);
    gload_lds16(bS[1] + koff, dst + 1024);
  };

  // ---- fragment read offsets. row stride 64B; swizzle chunk' = chunk ^ ((row>>1)&3),
  // with row = 16-aligned base + (lane&15) => (row>>1)&3 == (lane>>1)&3.
  int wr = wid >> 2, wc = wid & 3;
  int csw = (((lane >> 4) ^ ((lane >> 1) & 3)) << 4);   // swizzled chunk byte offset
  int aOff[8], bOff[4];
  #pragma unroll
  for (int m = 0; m < 8; ++m)
    aOff[m] = (((wr << 7) + (m << 4) + (lane & 15)) << 6) + csw;
  #pragma unroll
  for (int n = 0; n < 4; ++n)
    bOff[n] = (((wc << 6) + (n << 4) + (lane & 15)) << 6) + csw;

  f32x4 acc[8][4] = {};

  // prologue: stage tiles 0,1,2 (12 DMAs/wave)
  STAGE_A(0); STAGE_B(0);
  STAGE_A(1); STAGE_B(1);
  STAGE_A(2); STAGE_B(2);
  asm volatile("s_waitcnt vmcnt(8)" ::: "memory");   // tile 0 landed
  BAR();

  #pragma unroll 1
  for (int t = 0; t < NKT; ++t) {
    const char* sA = smem + A_BASE + ((t & 3) << 14);
    const char* sB = smem + B_BASE + ((t & 3) << 14);
    short8 af[8], bf[4];

    // ---- phase 0: frags m0-3 + all B, stage A(t+3), 16 MFMA
    #pragma unroll
    for (int m = 0; m < 4; ++m) af[m] = *(const short8*)(sA + aOff[m]);
    #pragma unroll
    for (int n = 0; n < 4; ++n) bf[n] = *(const short8*)(sB + bOff[n]);
    BAR();                              // all waves past last reads of slot (t-1)
    if (t + 3 < NKT) STAGE_A(t + 3);    // writes slot (t-1)%4 -- safe post-BAR
    asm volatile("s_waitcnt lgkmcnt(0)" ::: "memory");
    __builtin_amdgcn_sched_barrier(0);
    __builtin_amdgcn_s_setprio(1);
    #pragma unroll
    for (int m = 0; m < 4; ++m) {
      #pragma unroll
      for (int n = 0; n < 4; ++n)
        acc[m][n] = __builtin_amdgcn_mfma_f32_16x16x32_bf16(af[m], bf[n], acc[m][n], 0, 0, 0);
    }
    __builtin_amdgcn_s_setprio(0);

    // ---- phase 1: frags m4-7, boundary vmcnt, stage B(t+3), 16 MFMA
    #pragma unroll
    for (int m = 4; m < 8; ++m) af[m] = *(const short8*)(sA + aOff[m]);
    // confirm tile t+1 landed (newest outstanding: A(t+3), B(t+2), A(t+2))
    if (t < NKT - 3)       asm volatile("s_waitcnt vmcnt(6)" ::: "memory");
    else if (t == NKT - 3) asm volatile("s_waitcnt vmcnt(4)" ::: "memory");
    else                   asm volatile("s_waitcnt vmcnt(0)" ::: "memory");
    BAR();
    if (t + 3 < NKT) STAGE_B(t + 3);
    asm volatile("s_waitcnt lgkmcnt(0)" ::: "memory");
    __builtin_amdgcn_sched_barrier(0);
    __builtin_amdgcn_s_setprio(1);
    #pragma unroll
    for (int m = 4; m < 8; ++m) {
      #pragma unroll
      for (int n = 0; n < 4; ++n)
        acc[m][n] = __builtin_amdgcn_mfma_f32_16x16x32_bf16(af[m], bf[n], acc[m][n], 0, 0, 0);
    }
    __builtin_amdgcn_s_setprio(0);
  }

  // ---- epilogue ----
  float* ps = (float*)(smem + PS_OFF);
  if (tid < 256) {
    int p = m0 + tid;
    int b = p >> 12, h = (p >> 6) & 63, w = p & 63;
    const float* s2 = s2p + (b * HP + h) * WP + w;
    float s = 0.f;
    #pragma unroll
    for (int dy = 0; dy < 3; ++dy) {
      #pragma unroll
      for (int dx = 0; dx < 3; ++dx) s += s2[dy * WP + dx];
    }
    ps[tid] = s;
  }
  asm volatile("s_waitcnt lgkmcnt(0)" ::: "memory");
  BAR();

  float al = alpha[0];
  float scale = powf(16.0f / logf(257.0f), al);   // (sqrt(256)/log1p(256))^alpha

  int c0 = (wc << 6) + (lane & 15);
  int rb = (wr << 7) + ((lane >> 4) << 2);
  #pragma unroll
  for (int n = 0; n < 4; ++n) {
    int cn = c0 + (n << 4);
    float kq = ksq[cn] + EPSV;
    float bv = bias[cn];
    #pragma unroll
    for (int m = 0; m < 8; ++m) {
      f32x4 a = acc[m][n];
      #pragma unroll
      for (int j = 0; j < 4; ++j) {
        int rm = rb + (m << 4) + j;
        float dot = a[j];
        float dist = ps[rm] - 2.0f * dot + kq;
        float y = dot * dot / dist + bv;
        out[(size_t)(m0 + rm) * OO + cn] = y * scale;
      }
    }
  }
}

extern "C" void kernel_launch(void* const* d_in, const int* in_sizes, int n_in,
                              void* d_out, int out_size, void* d_ws, size_t ws_size,
                              hipStream_t stream) {
  const float* x = (const float*)d_in[0];
  const float* kern = (const float*)d_in[1];
  const float* bias = (const float*)d_in[2];
  const float* alpha = (const float*)d_in[3];
  float* out = (float*)d_out;

  char* ws = (char*)d_ws;
  unsigned short* xp  = (unsigned short*)ws;                 // 16*66*66*128*2 = 17,842,176 B
  unsigned short* wtb = (unsigned short*)(ws + 17842176);    // 256*1152*2    =    589,824 B
  float* s2p = (float*)(ws + 18432000);                      // 16*66*66*4    =    278,784 B
  float* ksq = (float*)(ws + 18710784);                      // 256*4         =      1,024 B

  (void)hipFuncSetAttribute((const void*)yat_main,
                            hipFuncAttributeMaxDynamicSharedMemorySize, SMEM_TOTAL);

  prep_x<<<1024, 256, 0, stream>>>(x, xp, s2p);
  prep_w<<<256, 256, 0, stream>>>(kern, wtb, ksq);
  yat_main<<<256, 512, SMEM_TOTAL, stream>>>(xp, wtb, s2p, ksq, bias, alpha, out);
}